// Round 10
// baseline (310.409 us; speedup 1.0000x reference)
//
#include <hip/hip_runtime.h>

// Criterion_BiNet — adjoint multi-scale dice, XCD-local + prefetch pipeline.
// inter = p · (A^4 t); sum_p = p · (A^2 1); sum_t = t · (A^2 1).
// K1 hpool_tbl: per (g,bd,wtile): H-axis box^4 for all 5 scales in regs
//    (shuffle halos), u8 out; + 1 block writes u2f tables.
// K2 wd_dot0: blocks [0,640) = mono; [640,10240) = swizzled scale units:
//    w=(bx&7)*1200+(bx>>3) -> unit u=w/5 (g,bh), q=w%5 (k41 first). Per block:
//    issue u8 tile loads, then ALL pred float4s into regs (latency hides under
//    the W-box^4 shuffle chain), then D-box^4 + reg-dot. q==4 fuses k5 scale +
//    dot0 + 18 closed-form wsums (u2f from global tbl).
// K3 fin_pre + K4 finalize.
// Slots: [0..35] inter (pair*6+s), [36..71] sum_p, [72..89] sum_t, [90] mono.

#define DIMB 4
#define DIMD 28
#define DIMH 160
#define DIMW 160
#define HW   (DIMH * DIMW)
#define DHW  (DIMD * HW)
#define VOL_N (DIMB * DHW)      // 2,867,200
#define PGRID 640
#define NSLOTS 91
#define DICE_EPS 1e-7
#define TBL_OFF (480 * 1024)

__device__ __forceinline__ float u2f(int pos, int k, int L) {
    if (k == 1) return 1.f;
    int r = k >> 1;
    float s = 0.f;
    for (int j = max(pos - r, 0); j <= min(pos + r, L - 1); ++j)
        s += (float)(min(j + r, L - 1) - max(j - r, 0) + 1);
    return s / (float)(k * k);
}

__device__ __forceinline__ float wave_sum(float v) {
#pragma unroll
    for (int o = 1; o < 64; o <<= 1) v += __shfl_xor(v, o, 64);
    return v;
}

template<int K>
__device__ __forceinline__ void box4_col(float (&x)[28]) {
    constexpr int R = K / 2;
    constexpr float INVK = 1.f / (float)K;
#pragma unroll
    for (int p = 0; p < 4; ++p) {
        float y[28];
        float s = 0.f;
#pragma unroll
        for (int j = 0; j <= R; ++j) s += x[j];
        y[0] = s;
#pragma unroll
        for (int i = 1; i < 28; ++i) {
            if (i + R < 28) s += x[i + R];
            if (i - R - 1 >= 0) s -= x[i - R - 1];
            y[i] = s;
        }
#pragma unroll
        for (int i = 0; i < 28; ++i) x[i] = y[i] * INVK;
    }
}

// ---------------- K1: H-axis box^4 (all 5 scales from one raw load) --------
template<int K>
__device__ __forceinline__ void hstore(const float (&raw)[40],
                                       unsigned char* __restrict__ ob,
                                       int l, int c, int wl, int h0)
{
    constexpr int R = K / 2;
    constexpr float INVK = 1.f / (float)K;
    float ox[40];
#pragma unroll
    for (int i = 0; i < 40; ++i) ox[i] = raw[i];
#pragma unroll
    for (int pass = 0; pass < 4; ++pass) {
        float lo[R], hi[R];
#pragma unroll
        for (int i = 0; i < R; ++i) {
            float a = __shfl(ox[40 - R + i], l - 16, 64);
            lo[i] = (c == 0) ? 0.f : a;
            float b = __shfl(ox[i], l + 16, 64);
            hi[i] = (c == 3) ? 0.f : b;
        }
#define HWIN(j) ((j) < R ? lo[(j)] : ((j) < R + 40 ? ox[(j) - R] : hi[(j) - R - 40]))
        float out[40];
        float s = 0.f;
#pragma unroll
        for (int j = 0; j <= 2 * R; ++j) s += HWIN(j);
        out[0] = s * INVK;
#pragma unroll
        for (int i = 1; i < 40; ++i) {
            s += HWIN(i + 2 * R) - HWIN(i - 1);
            out[i] = s * INVK;
        }
#undef HWIN
#pragma unroll
        for (int i = 0; i < 40; ++i) ox[i] = out[i];
    }
#pragma unroll
    for (int i = 0; i < 40; ++i)
        ob[(h0 + i) * DIMW + wl] = (unsigned char)__float2uint_rn(ox[i] * 255.f);
}

__global__ __launch_bounds__(256) void hpool_tbl(const float* __restrict__ g0,
    const float* __restrict__ g1, const float* __restrict__ g2,
    unsigned char* __restrict__ bufs, float* __restrict__ tbl)
{
    int bx = blockIdx.x;
    if (bx < 840) {
        int u = bx * 2 + (threadIdx.x >> 7);   // 1680 units = 3g * 112bd * 5wt
        int tt = threadIdx.x & 127;
        int g = u / 560, r = u - g * 560;
        int bd = r / 5, wt = r - bd * 5;
        const float* in = (g == 0) ? g0 : (g == 1) ? g1 : g2;
        int l = tt & 63, v = tt >> 6;
        int c = l >> 4, wl = v * 16 + (l & 15), h0 = c * 40;
        const float* base = in + (size_t)bd * HW + wt * 32;
        float raw[40];
#pragma unroll
        for (int i = 0; i < 40; ++i) raw[i] = base[(h0 + i) * DIMW + wl];
        unsigned char* ob = bufs + (size_t)g * 5 * VOL_N + (size_t)bd * HW + wt * 32;
        hstore<5> (raw, ob + 0 * (size_t)VOL_N, l, c, wl, h0);
        hstore<13>(raw, ob + 1 * (size_t)VOL_N, l, c, wl, h0);
        hstore<23>(raw, ob + 2 * (size_t)VOL_N, l, c, wl, h0);
        hstore<31>(raw, ob + 3 * (size_t)VOL_N, l, c, wl, h0);
        hstore<41>(raw, ob + 4 * (size_t)VOL_N, l, c, wl, h0);
    } else {
        // u2f tables: tbl[0..959] = cW[6][160]; tbl[960..1127] = cD[6][28]
        const int KDa[6] = {1, 1, 3, 5, 7, 9};
        const int KHa[6] = {1, 5, 13, 23, 31, 41};
        for (int e = threadIdx.x; e < 1128; e += 256) {
            if (e < 960) tbl[e] = u2f(e % 160, KHa[e / 160], DIMH);
            else {
                int q = e - 960;
                tbl[e] = u2f(q % 28, KDa[q / 28], DIMD);
            }
        }
    }
}

// ---------------- K2: W-box^4 from preloaded u8 regs ----------------
template<int K>
__device__ __forceinline__ void wpool_S(const unsigned int (&ub)[5],
    float (*S)[164], int l, int rr, int c, bool act)
{
    constexpr int R = K / 2;
    float ox[20];
#pragma unroll
    for (int q = 0; q < 5; ++q) {
#pragma unroll
        for (int j = 0; j < 4; ++j)
            ox[4 * q + j] = (float)((ub[q] >> (8 * j)) & 0xFFu);
    }
#pragma unroll
    for (int pass = 0; pass < 4; ++pass) {
        const float scl = (pass == 0) ? (1.f / ((float)K * 255.f)) : (1.f / (float)K);
        float lo[R], hi[R];
#pragma unroll
        for (int i = 0; i < R; ++i) {
            float a = __shfl(ox[20 - R + i], l - 1, 64);
            lo[i] = (c == 0) ? 0.f : a;
            float b = __shfl(ox[i], l + 1, 64);
            hi[i] = (c == 7) ? 0.f : b;
        }
#define WWIN(j) ((j) < R ? lo[(j)] : ((j) < R + 20 ? ox[(j) - R] : hi[(j) - R - 20]))
        float out[20];
        float s = 0.f;
#pragma unroll
        for (int j = 0; j <= 2 * R; ++j) s += WWIN(j);
        out[0] = s * scl;
#pragma unroll
        for (int i = 1; i < 20; ++i) {
            s += WWIN(i + 2 * R) - WWIN(i - 1);
            out[i] = s * scl;
        }
#undef WWIN
#pragma unroll
        for (int i = 0; i < 20; ++i) ox[i] = out[i];
    }
    if (act) {
#pragma unroll
        for (int i = 0; i < 20; ++i) S[rr][c * 20 + i] = ox[i];
    }
    __syncthreads();
}

template<int K, int KD>
__device__ __forceinline__ void wd_scale(const unsigned int (&ub)[5],
    const float4 (&rc)[5], const float4 (&rp)[5],
    float (*S)[164], float* red2, int t, int l, int wid, int rr, int c, bool act,
    double* __restrict__ partials, int slot_c, int slot_p, int bh)
{
    wpool_S<K>(ub, S, l, rr, c, act);
    if constexpr (KD > 1) {
        if (t < DIMW) {
            float col[28];
#pragma unroll
            for (int j = 0; j < 28; ++j) col[j] = S[j][t];
            box4_col<KD>(col);
#pragma unroll
            for (int j = 0; j < 28; ++j) S[j][t] = col[j];
        }
        __syncthreads();
    }
    float aic = 0.f, aip = 0.f;
#pragma unroll
    for (int qq = 0; qq < 5; ++qq) {
        int e4c = min(t + 256 * qq, 1119);
        int dd = e4c / 40, w4 = e4c - dd * 40;
        const float4 sv = *(const float4*)&S[dd][4 * w4];
        aic += rc[qq].x * sv.x + rc[qq].y * sv.y + rc[qq].z * sv.z + rc[qq].w * sv.w;
        aip += rp[qq].x * sv.x + rp[qq].y * sv.y + rp[qq].z * sv.z + rp[qq].w * sv.w;
    }
    float r1 = wave_sum(aic), r2 = wave_sum(aip);
    if (l == 0) { red2[wid * 2] = r1; red2[wid * 2 + 1] = r2; }
    __syncthreads();
    if (t < 2) {
        double rv = (double)red2[t] + red2[2 + t] + red2[4 + t] + red2[6 + t];
        partials[(size_t)(t == 0 ? slot_c : slot_p) * PGRID + bh] = rv;
    }
}

__global__ __launch_bounds__(256) void wd_dot0(const unsigned char* __restrict__ bufs,
    const float* __restrict__ pc0, const float* __restrict__ pp0,
    const float* __restrict__ pc1, const float* __restrict__ pp1,
    const float* __restrict__ pc2, const float* __restrict__ pp2,
    const float* __restrict__ tr0, const float* __restrict__ tr1,
    const float* __restrict__ tr2, const float* __restrict__ o6,
    const float* __restrict__ tbl, double* __restrict__ partials)
{
    __shared__ __align__(16) float S[DIMD][164];
    __shared__ float redS[4][24];
    int bx0 = blockIdx.x;
    int t = threadIdx.x;

    if (bx0 < 640) {              // mono blocks: BW-bound, overlap wd latency
        int mb = bx0;
        const int N4 = VOL_N / 4, PB = N4 / DIMB;
        float acc = 0.f;
        const float4* p = (const float4*)o6;
        for (int i = mb * 256 + t; i < N4; i += PGRID * 256) {
            int b = i / PB, r4 = i - b * PB;
            size_t a = (size_t)(b * 6) * PB + r4;
            float4 prev = p[a];
#pragma unroll
            for (int cc = 1; cc < 6; ++cc) {
                float4 cur = p[a + (size_t)cc * PB];
                acc += fmaxf(prev.x - cur.x, 0.f) + fmaxf(prev.y - cur.y, 0.f)
                     + fmaxf(prev.z - cur.z, 0.f) + fmaxf(prev.w - cur.w, 0.f);
                prev = cur;
            }
        }
        float rv = wave_sum(acc * 2.f);
        int lane = t & 63, wid = t >> 6;
        if (lane == 0) redS[wid][0] = rv;
        __syncthreads();
        if (t == 0)
            partials[(size_t)90 * PGRID + mb] =
                (double)redS[0][0] + redS[1][0] + redS[2][0] + redS[3][0];
        return;
    }

    // XCD-local swizzle: unit (g,bh) gets 5 consecutive same-XCD slots
    int bxx = bx0 - 640;                      // 0..9599
    int w = (bxx & 7) * 1200 + (bxx >> 3);    // bijective (9600 = 8*1200)
    int u = w / 5, q = w - u * 5;             // q: 0=k41,1=k31,2=k23,3=k13,4=k5
    int g = u / PGRID, bh = u - g * PGRID;
    int b = bh / DIMH, h = bh - b * DIMH;
    const float* pc = (g == 0) ? pc0 : (g == 1) ? pc1 : pc2;
    const float* pp = (g == 0) ? pp0 : (g == 1) ? pp1 : pp2;
    size_t base0 = (size_t)b * DHW + (size_t)h * DIMW;
    int base4 = b * (DHW / 4) + h * 40;
    const float4* c4 = (const float4*)pc;
    const float4* p4 = (const float4*)pp;
    int l = t & 63, wid = t >> 6;
    int rr = wid * 7 + (l >> 3), c = l & 7;
    bool act = (l < 56);
    int sbuf = (q < 4) ? (4 - q) : 0;         // k41,k31,k23,k13,k5
    const unsigned char* tb = bufs + (size_t)(g * 5 + sbuf) * VOL_N
                            + base0 + (size_t)rr * HW + c * 20;

    // 1) u8 tile loads first (oldest in vm queue)
    unsigned int ub[5] = {0u, 0u, 0u, 0u, 0u};
    if (act) {
#pragma unroll
        for (int qq = 0; qq < 5; ++qq) ub[qq] = *(const unsigned int*)(tb + 4 * qq);
    }
    // 2) pred slab -> registers; latency hides under the shuffle chain
    const float4 Z4 = make_float4(0.f, 0.f, 0.f, 0.f);
    float4 rc[5], rp[5];
#pragma unroll
    for (int qq = 0; qq < 5; ++qq) {
        int e4 = t + 256 * qq;
        bool v = e4 < 1120;
        int e4c = min(e4, 1119);
        int dd = e4c / 40, w4 = e4c - dd * 40;
        int fi = base4 + dd * (HW / 4) + w4;
        rc[qq] = v ? c4[fi] : Z4;
        rp[qq] = v ? p4[fi] : Z4;
    }

    if (q < 4) {
        int s = 5 - q;
        int slot_c = (2 * g) * 6 + s, slot_p = (2 * g + 1) * 6 + s;
        switch (q) {
            case 0: wd_scale<41, 9>(ub, rc, rp, S, &redS[0][0], t, l, wid, rr, c, act, partials, slot_c, slot_p, bh); break;
            case 1: wd_scale<31, 7>(ub, rc, rp, S, &redS[0][0], t, l, wid, rr, c, act, partials, slot_c, slot_p, bh); break;
            case 2: wd_scale<23, 5>(ub, rc, rp, S, &redS[0][0], t, l, wid, rr, c, act, partials, slot_c, slot_p, bh); break;
            default: wd_scale<13, 3>(ub, rc, rp, S, &redS[0][0], t, l, wid, rr, c, act, partials, slot_c, slot_p, bh); break;
        }
        return;
    }

    // q == 4: k5 scale + dot0 + 18 weighted sums (tables from global tbl)
    const float* tr = (g == 0) ? tr0 : (g == 1) ? tr1 : tr2;
    const float4* t4 = (const float4*)tr;
    wpool_S<5>(ub, S, l, rr, c, act);
    float vals[22];
#pragma unroll
    for (int i = 0; i < 22; ++i) vals[i] = 0.f;
#pragma unroll
    for (int qq = 0; qq < 5; ++qq) {
        int e4 = t + 256 * qq;
        bool v = e4 < 1120;
        int e4c = min(e4, 1119);
        int dd = e4c / 40, w4 = e4c - dd * 40;
        int fi = base4 + dd * (HW / 4) + w4;
        float4 vt = v ? t4[fi] : Z4;
        const float4 sv = *(const float4*)&S[dd][4 * w4];
        vals[0] += rc[qq].x*sv.x + rc[qq].y*sv.y + rc[qq].z*sv.z + rc[qq].w*sv.w;
        vals[1] += rp[qq].x*sv.x + rp[qq].y*sv.y + rp[qq].z*sv.z + rp[qq].w*sv.w;
        vals[2] += rc[qq].x*vt.x + rc[qq].y*vt.y + rc[qq].z*vt.z + rc[qq].w*vt.w;
        vals[3] += rp[qq].x*vt.x + rp[qq].y*vt.y + rp[qq].z*vt.z + rp[qq].w*vt.w;
#pragma unroll
        for (int s = 0; s < 6; ++s) {
            float cdh = tbl[960 + s * 28 + dd];
            const float4 cw = *(const float4*)(tbl + s * 160 + 4 * w4);
            vals[4 + s]  += cdh * (cw.x*rc[qq].x + cw.y*rc[qq].y + cw.z*rc[qq].z + cw.w*rc[qq].w);
            vals[10 + s] += cdh * (cw.x*rp[qq].x + cw.y*rp[qq].y + cw.z*rp[qq].z + cw.w*rp[qq].w);
            vals[16 + s] += cdh * (cw.x*vt.x + cw.y*vt.y + cw.z*vt.z + cw.w*vt.w);
        }
    }
#pragma unroll
    for (int i = 0; i < 22; ++i) {
        float rv = wave_sum(vals[i]);
        if (l == 0) redS[wid][i] = rv;
    }
    __syncthreads();
    if (t < 22) {
        double rv = (double)redS[0][t] + redS[1][t] + redS[2][t] + redS[3][t];
        double fac = 1.0;
        int slot;
        if (t == 0) slot = (2 * g) * 6 + 1;
        else if (t == 1) slot = (2 * g + 1) * 6 + 1;
        else if (t == 2) slot = (2 * g) * 6;
        else if (t == 3) slot = (2 * g + 1) * 6;
        else {
            int i = t - 4, vv = i / 6, s = i % 6;
            fac = (double)tbl[s * 160 + h];
            slot = (vv == 0) ? 36 + (2 * g) * 6 + s
                 : (vv == 1) ? 36 + (2 * g + 1) * 6 + s
                             : 72 + g * 6 + s;
        }
        partials[(size_t)slot * PGRID + bh] = rv * fac;
    }
}

// ---------------- K3/K4: reduction tail ----------------
__global__ __launch_bounds__(64) void fin_pre(const double* __restrict__ partials,
                                              double* __restrict__ ssum)
{
    int slot = blockIdx.x, t = threadIdx.x;
    double a = 0.0;
    for (int i = t; i < PGRID; i += 64) a += partials[(size_t)slot * PGRID + i];
#pragma unroll
    for (int o = 1; o < 64; o <<= 1) a += __shfl_xor(a, o, 64);
    if (t == 0) ssum[slot] = a;
}

__global__ void finalize(const double* __restrict__ ssum,
                         const float* __restrict__ off_a,
                         const float* __restrict__ off_b,
                         const float* __restrict__ off_ta,
                         const float* __restrict__ off_tb,
                         float* __restrict__ out)
{
    if (threadIdx.x == 0) {
        double loss = 0.0;
        for (int pair = 0; pair < 6; ++pair) {
            for (int s = 0; s < 6; ++s) {
                double inter = ssum[pair * 6 + s];
                double sp = ssum[36 + pair * 6 + s];
                double st = ssum[72 + (pair / 2) * 6 + s];
                loss += 0.2 * (1.0 - 2.0 * inter / (sp + st + DICE_EPS)) / 6.0;
            }
        }
        loss += 0.1 * (ssum[90] / (double)VOL_N);
        double oa = 0.0, ob = 0.0;
        for (int i = 0; i < 12; ++i) {
            oa += fabs((double)off_a[i] - (double)off_ta[i]);
            ob += fabs((double)off_b[i] - (double)off_tb[i]);
        }
        loss += 0.1 * (oa / 12.0) + 0.1 * (ob / 12.0);
        out[0] = (float)loss;
    }
}

extern "C" void kernel_launch(void* const* d_in, const int* in_sizes, int n_in,
                              void* d_out, int out_size, void* d_ws, size_t ws_size,
                              hipStream_t stream)
{
    double* partials = (double*)d_ws;                   // 91*640*8 = 465,920 B
    double* ssum = partials + (size_t)NSLOTS * PGRID;   // +91*8 < 480 KB
    float* tbl = (float*)((char*)d_ws + TBL_OFF);       // 1128 floats
    unsigned char* bufs = (unsigned char*)d_ws + 512 * 1024;  // 15*VOL_N u8 = 43 MB

    const float* pred[6] = {(const float*)d_in[0], (const float*)d_in[1],
                            (const float*)d_in[3], (const float*)d_in[4],
                            (const float*)d_in[6], (const float*)d_in[7]};
    const float* gt[3] = {(const float*)d_in[2], (const float*)d_in[5],
                          (const float*)d_in[8]};

    hpool_tbl<<<841, 256, 0, stream>>>(gt[0], gt[1], gt[2], bufs, tbl);
    wd_dot0<<<10240, 256, 0, stream>>>(bufs, pred[0], pred[1], pred[2], pred[3],
                                       pred[4], pred[5], gt[0], gt[1], gt[2],
                                       (const float*)d_in[9], tbl, partials);
    fin_pre<<<NSLOTS, 64, 0, stream>>>(partials, ssum);
    finalize<<<1, 64, 0, stream>>>(ssum,
                                   (const float*)d_in[10], (const float*)d_in[11],
                                   (const float*)d_in[12], (const float*)d_in[13],
                                   (float*)d_out);
}

// Round 11
// 135.700 us; speedup vs baseline: 2.2875x; 2.2875x over previous
//
#include <hip/hip_runtime.h>

// Criterion_BiNet — adjoint multi-scale dice. R11 = R9 structure + XCD swizzle.
// inter = p · (A^4 t); sum_p = p · (A^2 1); sum_t = t · (A^2 1).
// K1 hpool_tbl: per (g,bd,wtile): H-axis box^4 for all 5 scales in regs
//    (shuffle halos), u8 out; + 1 block writes u2f tables.
// K2 wd_dot0: blocks [0,640) = mono; [640,10240) = swizzled scale units:
//    w=(bx&7)*1200+(bx>>3) -> unit u=w/5 (g,bh), q=w%5. The 5 blocks of a
//    unit land on ONE XCD, temporally adjacent -> pred slab fetched once/L2.
//    Preds are loaded from global AFTER pooling (low VGPR, occ ~40%).
//    q<4: u8 tile -> W-box^4 (shuffle, scale hoisted) -> D-box^4 -> dot.
//    q==4: k5 + dot0 + 18 closed-form wsums (u2f from global tbl).
// K3 fin_pre + K4 finalize.
// Slots: [0..35] inter (pair*6+s), [36..71] sum_p, [72..89] sum_t, [90] mono.

#define DIMB 4
#define DIMD 28
#define DIMH 160
#define DIMW 160
#define HW   (DIMH * DIMW)
#define DHW  (DIMD * HW)
#define VOL_N (DIMB * DHW)      // 2,867,200
#define PGRID 640
#define NSLOTS 91
#define DICE_EPS 1e-7
#define TBL_OFF (480 * 1024)

__device__ __forceinline__ float u2f(int pos, int k, int L) {
    if (k == 1) return 1.f;
    int r = k >> 1;
    float s = 0.f;
    for (int j = max(pos - r, 0); j <= min(pos + r, L - 1); ++j)
        s += (float)(min(j + r, L - 1) - max(j - r, 0) + 1);
    return s / (float)(k * k);
}

__device__ __forceinline__ float wave_sum(float v) {
#pragma unroll
    for (int o = 1; o < 64; o <<= 1) v += __shfl_xor(v, o, 64);
    return v;
}

template<int K>
__device__ __forceinline__ void box4_col(float (&x)[28]) {
    constexpr int R = K / 2;
    constexpr float INVK = 1.f / (float)K;
#pragma unroll
    for (int p = 0; p < 4; ++p) {
        float y[28];
        float s = 0.f;
#pragma unroll
        for (int j = 0; j <= R; ++j) s += x[j];
        y[0] = s;
#pragma unroll
        for (int i = 1; i < 28; ++i) {
            if (i + R < 28) s += x[i + R];
            if (i - R - 1 >= 0) s -= x[i - R - 1];
            y[i] = s;
        }
#pragma unroll
        for (int i = 0; i < 28; ++i) x[i] = y[i] * INVK;
    }
}

// ---------------- K1: H-axis box^4 (all 5 scales from one raw load) --------
template<int K>
__device__ __forceinline__ void hstore(const float (&raw)[40],
                                       unsigned char* __restrict__ ob,
                                       int l, int c, int wl, int h0)
{
    constexpr int R = K / 2;
    constexpr float INVK = 1.f / (float)K;
    float ox[40];
#pragma unroll
    for (int i = 0; i < 40; ++i) ox[i] = raw[i];
#pragma unroll
    for (int pass = 0; pass < 4; ++pass) {
        float lo[R], hi[R];
#pragma unroll
        for (int i = 0; i < R; ++i) {
            float a = __shfl(ox[40 - R + i], l - 16, 64);
            lo[i] = (c == 0) ? 0.f : a;
            float b = __shfl(ox[i], l + 16, 64);
            hi[i] = (c == 3) ? 0.f : b;
        }
#define HWIN(j) ((j) < R ? lo[(j)] : ((j) < R + 40 ? ox[(j) - R] : hi[(j) - R - 40]))
        float out[40];
        float s = 0.f;
#pragma unroll
        for (int j = 0; j <= 2 * R; ++j) s += HWIN(j);
        out[0] = s * INVK;
#pragma unroll
        for (int i = 1; i < 40; ++i) {
            s += HWIN(i + 2 * R) - HWIN(i - 1);
            out[i] = s * INVK;
        }
#undef HWIN
#pragma unroll
        for (int i = 0; i < 40; ++i) ox[i] = out[i];
    }
#pragma unroll
    for (int i = 0; i < 40; ++i)
        ob[(h0 + i) * DIMW + wl] = (unsigned char)__float2uint_rn(ox[i] * 255.f);
}

__global__ __launch_bounds__(256) void hpool_tbl(const float* __restrict__ g0,
    const float* __restrict__ g1, const float* __restrict__ g2,
    unsigned char* __restrict__ bufs, float* __restrict__ tbl)
{
    int bx = blockIdx.x;
    if (bx < 840) {
        int u = bx * 2 + (threadIdx.x >> 7);   // 1680 units = 3g * 112bd * 5wt
        int tt = threadIdx.x & 127;
        int g = u / 560, r = u - g * 560;
        int bd = r / 5, wt = r - bd * 5;
        const float* in = (g == 0) ? g0 : (g == 1) ? g1 : g2;
        int l = tt & 63, v = tt >> 6;
        int c = l >> 4, wl = v * 16 + (l & 15), h0 = c * 40;
        const float* base = in + (size_t)bd * HW + wt * 32;
        float raw[40];
#pragma unroll
        for (int i = 0; i < 40; ++i) raw[i] = base[(h0 + i) * DIMW + wl];
        unsigned char* ob = bufs + (size_t)g * 5 * VOL_N + (size_t)bd * HW + wt * 32;
        hstore<5> (raw, ob + 0 * (size_t)VOL_N, l, c, wl, h0);
        hstore<13>(raw, ob + 1 * (size_t)VOL_N, l, c, wl, h0);
        hstore<23>(raw, ob + 2 * (size_t)VOL_N, l, c, wl, h0);
        hstore<31>(raw, ob + 3 * (size_t)VOL_N, l, c, wl, h0);
        hstore<41>(raw, ob + 4 * (size_t)VOL_N, l, c, wl, h0);
    } else {
        // u2f tables: tbl[0..959] = cW[6][160]; tbl[960..1127] = cD[6][28]
        const int KDa[6] = {1, 1, 3, 5, 7, 9};
        const int KHa[6] = {1, 5, 13, 23, 31, 41};
        for (int e = threadIdx.x; e < 1128; e += 256) {
            if (e < 960) tbl[e] = u2f(e % 160, KHa[e / 160], DIMH);
            else {
                int q = e - 960;
                tbl[e] = u2f(q % 28, KDa[q / 28], DIMD);
            }
        }
    }
}

// ---------------- K2: W-box^4 to S (shuffle halos, scale hoisted) ----------
template<int K>
__device__ __forceinline__ void wpool_to_S(const unsigned char* __restrict__ tb,
    float (*S)[164], int t, int l, int rr, int c, bool act)
{
    constexpr int R = K / 2;
    const float INV = 1.0f / (255.0f * (float)K * (float)K * (float)K * (float)K);
    float ox[20];
#pragma unroll
    for (int i = 0; i < 20; ++i) ox[i] = 0.f;
    if (act) {
        unsigned int u[5];
#pragma unroll
        for (int q = 0; q < 5; ++q) u[q] = *(const unsigned int*)(tb + 4 * q);
#pragma unroll
        for (int q = 0; q < 5; ++q) {
#pragma unroll
            for (int j = 0; j < 4; ++j)
                ox[4 * q + j] = (float)((u[q] >> (8 * j)) & 0xFFu);
        }
    }
#pragma unroll
    for (int pass = 0; pass < 4; ++pass) {
        float lo[R], hi[R];
#pragma unroll
        for (int i = 0; i < R; ++i) {
            float a = __shfl(ox[20 - R + i], l - 1, 64);
            lo[i] = (c == 0) ? 0.f : a;
            float b = __shfl(ox[i], l + 1, 64);
            hi[i] = (c == 7) ? 0.f : b;
        }
#define WWIN(j) ((j) < R ? lo[(j)] : ((j) < R + 20 ? ox[(j) - R] : hi[(j) - R - 20]))
        float out[20];
        float s = 0.f;
#pragma unroll
        for (int j = 0; j <= 2 * R; ++j) s += WWIN(j);
        out[0] = s;
#pragma unroll
        for (int i = 1; i < 20; ++i) {
            s += WWIN(i + 2 * R) - WWIN(i - 1);
            out[i] = s;
        }
#undef WWIN
#pragma unroll
        for (int i = 0; i < 20; ++i) ox[i] = out[i];
    }
    if (act) {
#pragma unroll
        for (int i = 0; i < 20; ++i) S[rr][c * 20 + i] = ox[i] * INV;
    }
    __syncthreads();
}

template<int K, int KD>
__device__ __forceinline__ void wd_scale(const unsigned char* __restrict__ tb,
    const float4* __restrict__ c4, const float4* __restrict__ p4, int base4,
    float (*S)[164], float* red2, int t, int l, int wid, int rr, int c, bool act,
    double* __restrict__ partials, int slot_c, int slot_p, int bh)
{
    wpool_to_S<K>(tb, S, t, l, rr, c, act);
    if constexpr (KD > 1) {
        if (t < DIMW) {
            float col[28];
#pragma unroll
            for (int j = 0; j < 28; ++j) col[j] = S[j][t];
            box4_col<KD>(col);
#pragma unroll
            for (int j = 0; j < 28; ++j) S[j][t] = col[j];
        }
        __syncthreads();
    }
    float aic = 0.f, aip = 0.f;
    for (int e4 = t; e4 < 1120; e4 += 256) {
        int dd = e4 / 40, w4 = e4 - dd * 40;
        int fi = base4 + dd * (HW / 4) + w4;
        float4 vc = c4[fi], vp = p4[fi];
        const float4 sv = *(const float4*)&S[dd][4 * w4];
        aic += vc.x * sv.x + vc.y * sv.y + vc.z * sv.z + vc.w * sv.w;
        aip += vp.x * sv.x + vp.y * sv.y + vp.z * sv.z + vp.w * sv.w;
    }
    float r1 = wave_sum(aic), r2 = wave_sum(aip);
    if (l == 0) { red2[wid * 2] = r1; red2[wid * 2 + 1] = r2; }
    __syncthreads();
    if (t < 2) {
        double rv = (double)red2[t] + red2[2 + t] + red2[4 + t] + red2[6 + t];
        partials[(size_t)(t == 0 ? slot_c : slot_p) * PGRID + bh] = rv;
    }
}

__global__ __launch_bounds__(256) void wd_dot0(const unsigned char* __restrict__ bufs,
    const float* __restrict__ pc0, const float* __restrict__ pp0,
    const float* __restrict__ pc1, const float* __restrict__ pp1,
    const float* __restrict__ pc2, const float* __restrict__ pp2,
    const float* __restrict__ tr0, const float* __restrict__ tr1,
    const float* __restrict__ tr2, const float* __restrict__ o6,
    const float* __restrict__ tbl, double* __restrict__ partials)
{
    __shared__ __align__(16) float S[DIMD][164];
    __shared__ float redS[4][24];
    int bx0 = blockIdx.x;
    int t = threadIdx.x;

    if (bx0 < 640) {              // mono blocks: BW-bound, overlap wd latency
        int mb = bx0;
        const int N4 = VOL_N / 4, PB = N4 / DIMB;
        float acc = 0.f;
        const float4* p = (const float4*)o6;
        for (int i = mb * 256 + t; i < N4; i += PGRID * 256) {
            int b = i / PB, r4 = i - b * PB;
            size_t a = (size_t)(b * 6) * PB + r4;
            float4 prev = p[a];
#pragma unroll
            for (int cc = 1; cc < 6; ++cc) {
                float4 cur = p[a + (size_t)cc * PB];
                acc += fmaxf(prev.x - cur.x, 0.f) + fmaxf(prev.y - cur.y, 0.f)
                     + fmaxf(prev.z - cur.z, 0.f) + fmaxf(prev.w - cur.w, 0.f);
                prev = cur;
            }
        }
        float rv = wave_sum(acc * 2.f);
        int lane = t & 63, wid = t >> 6;
        if (lane == 0) redS[wid][0] = rv;
        __syncthreads();
        if (t == 0)
            partials[(size_t)90 * PGRID + mb] =
                (double)redS[0][0] + redS[1][0] + redS[2][0] + redS[3][0];
        return;
    }

    // XCD-local swizzle: the 5 blocks of unit (g,bh) land on one XCD,
    // temporally adjacent (w consecutive -> bxx stride 8).
    int bxx = bx0 - 640;                      // 0..9599
    int w = (bxx & 7) * 1200 + (bxx >> 3);    // bijective (9600 = 8*1200)
    int u = w / 5, q = w - u * 5;             // q: 0=k41,1=k31,2=k23,3=k13,4=k5
    int g = u / PGRID, bh = u - g * PGRID;
    int b = bh / DIMH, h = bh - b * DIMH;
    const float* pc = (g == 0) ? pc0 : (g == 1) ? pc1 : pc2;
    const float* pp = (g == 0) ? pp0 : (g == 1) ? pp1 : pp2;
    size_t base0 = (size_t)b * DHW + (size_t)h * DIMW;
    int base4 = b * (DHW / 4) + h * 40;
    const float4* c4 = (const float4*)pc;
    const float4* p4 = (const float4*)pp;
    int l = t & 63, wid = t >> 6;
    int rr = wid * 7 + (l >> 3), c = l & 7;
    bool act = (l < 56);
    int sbuf = (q < 4) ? (4 - q) : 0;         // k41,k31,k23,k13,k5
    const unsigned char* tb = bufs + (size_t)(g * 5 + sbuf) * VOL_N
                            + base0 + (size_t)rr * HW + c * 20;

    if (q < 4) {
        int s = 5 - q;
        int slot_c = (2 * g) * 6 + s, slot_p = (2 * g + 1) * 6 + s;
        switch (q) {
            case 0: wd_scale<41, 9>(tb, c4, p4, base4, S, &redS[0][0], t, l, wid, rr, c, act, partials, slot_c, slot_p, bh); break;
            case 1: wd_scale<31, 7>(tb, c4, p4, base4, S, &redS[0][0], t, l, wid, rr, c, act, partials, slot_c, slot_p, bh); break;
            case 2: wd_scale<23, 5>(tb, c4, p4, base4, S, &redS[0][0], t, l, wid, rr, c, act, partials, slot_c, slot_p, bh); break;
            default: wd_scale<13, 3>(tb, c4, p4, base4, S, &redS[0][0], t, l, wid, rr, c, act, partials, slot_c, slot_p, bh); break;
        }
        return;
    }

    // q == 4: k5 pool + fused dot0 + 18 weighted sums (tables from global)
    const float* tr = (g == 0) ? tr0 : (g == 1) ? tr1 : tr2;
    const float4* t4 = (const float4*)tr;
    wpool_to_S<5>(tb, S, t, l, rr, c, act);
    float vals[22];
#pragma unroll
    for (int i = 0; i < 22; ++i) vals[i] = 0.f;
    for (int e4 = t; e4 < 1120; e4 += 256) {
        int dd = e4 / 40, w4 = e4 - dd * 40;
        int fi = base4 + dd * (HW / 4) + w4;
        float4 vc = c4[fi], vp = p4[fi], vt = t4[fi];
        const float4 sv = *(const float4*)&S[dd][4 * w4];
        vals[0] += vc.x*sv.x + vc.y*sv.y + vc.z*sv.z + vc.w*sv.w;
        vals[1] += vp.x*sv.x + vp.y*sv.y + vp.z*sv.z + vp.w*sv.w;
        vals[2] += vc.x*vt.x + vc.y*vt.y + vc.z*vt.z + vc.w*vt.w;
        vals[3] += vp.x*vt.x + vp.y*vt.y + vp.z*vt.z + vp.w*vt.w;
#pragma unroll
        for (int s = 0; s < 6; ++s) {
            float cdh = tbl[960 + s * 28 + dd];
            const float4 cw = *(const float4*)(tbl + s * 160 + 4 * w4);
            vals[4 + s]  += cdh * (cw.x*vc.x + cw.y*vc.y + cw.z*vc.z + cw.w*vc.w);
            vals[10 + s] += cdh * (cw.x*vp.x + cw.y*vp.y + cw.z*vp.z + cw.w*vp.w);
            vals[16 + s] += cdh * (cw.x*vt.x + cw.y*vt.y + cw.z*vt.z + cw.w*vt.w);
        }
    }
#pragma unroll
    for (int i = 0; i < 22; ++i) {
        float rv = wave_sum(vals[i]);
        if (l == 0) redS[wid][i] = rv;
    }
    __syncthreads();
    if (t < 22) {
        double rv = (double)redS[0][t] + redS[1][t] + redS[2][t] + redS[3][t];
        double fac = 1.0;
        int slot;
        if (t == 0) slot = (2 * g) * 6 + 1;
        else if (t == 1) slot = (2 * g + 1) * 6 + 1;
        else if (t == 2) slot = (2 * g) * 6;
        else if (t == 3) slot = (2 * g + 1) * 6;
        else {
            int i = t - 4, vv = i / 6, s = i % 6;
            fac = (double)tbl[s * 160 + h];
            slot = (vv == 0) ? 36 + (2 * g) * 6 + s
                 : (vv == 1) ? 36 + (2 * g + 1) * 6 + s
                             : 72 + g * 6 + s;
        }
        partials[(size_t)slot * PGRID + bh] = rv * fac;
    }
}

// ---------------- K3/K4: reduction tail ----------------
__global__ __launch_bounds__(64) void fin_pre(const double* __restrict__ partials,
                                              double* __restrict__ ssum)
{
    int slot = blockIdx.x, t = threadIdx.x;
    double a = 0.0;
    for (int i = t; i < PGRID; i += 64) a += partials[(size_t)slot * PGRID + i];
#pragma unroll
    for (int o = 1; o < 64; o <<= 1) a += __shfl_xor(a, o, 64);
    if (t == 0) ssum[slot] = a;
}

__global__ void finalize(const double* __restrict__ ssum,
                         const float* __restrict__ off_a,
                         const float* __restrict__ off_b,
                         const float* __restrict__ off_ta,
                         const float* __restrict__ off_tb,
                         float* __restrict__ out)
{
    if (threadIdx.x == 0) {
        double loss = 0.0;
        for (int pair = 0; pair < 6; ++pair) {
            for (int s = 0; s < 6; ++s) {
                double inter = ssum[pair * 6 + s];
                double sp = ssum[36 + pair * 6 + s];
                double st = ssum[72 + (pair / 2) * 6 + s];
                loss += 0.2 * (1.0 - 2.0 * inter / (sp + st + DICE_EPS)) / 6.0;
            }
        }
        loss += 0.1 * (ssum[90] / (double)VOL_N);
        double oa = 0.0, ob = 0.0;
        for (int i = 0; i < 12; ++i) {
            oa += fabs((double)off_a[i] - (double)off_ta[i]);
            ob += fabs((double)off_b[i] - (double)off_tb[i]);
        }
        loss += 0.1 * (oa / 12.0) + 0.1 * (ob / 12.0);
        out[0] = (float)loss;
    }
}

extern "C" void kernel_launch(void* const* d_in, const int* in_sizes, int n_in,
                              void* d_out, int out_size, void* d_ws, size_t ws_size,
                              hipStream_t stream)
{
    double* partials = (double*)d_ws;                   // 91*640*8 = 465,920 B
    double* ssum = partials + (size_t)NSLOTS * PGRID;   // +91*8 < 480 KB
    float* tbl = (float*)((char*)d_ws + TBL_OFF);       // 1128 floats
    unsigned char* bufs = (unsigned char*)d_ws + 512 * 1024;  // 15*VOL_N u8 = 43 MB

    const float* pred[6] = {(const float*)d_in[0], (const float*)d_in[1],
                            (const float*)d_in[3], (const float*)d_in[4],
                            (const float*)d_in[6], (const float*)d_in[7]};
    const float* gt[3] = {(const float*)d_in[2], (const float*)d_in[5],
                          (const float*)d_in[8]};

    hpool_tbl<<<841, 256, 0, stream>>>(gt[0], gt[1], gt[2], bufs, tbl);
    wd_dot0<<<10240, 256, 0, stream>>>(bufs, pred[0], pred[1], pred[2], pred[3],
                                       pred[4], pred[5], gt[0], gt[1], gt[2],
                                       (const float*)d_in[9], tbl, partials);
    fin_pre<<<NSLOTS, 64, 0, stream>>>(partials, ssum);
    finalize<<<1, 64, 0, stream>>>(ssum,
                                   (const float*)d_in[10], (const float*)d_in[11],
                                   (const float*)d_in[12], (const float*)d_in[13],
                                   (float*)d_out);
}

// Round 12
// 133.266 us; speedup vs baseline: 2.3292x; 1.0183x over previous
//
#include <hip/hip_runtime.h>

// Criterion_BiNet — adjoint multi-scale dice. R12 = R11 minus q4-fusion:
// uniform scale blocks + dedicated streaming (dot0/wsum, mono) tail blocks.
// inter = p · (A^4 t); sum_p = p · (A^2 1); sum_t = t · (A^2 1).
// K1 hpool_tbl: H-axis box^4 for all 5 scales (shuffle halos), u8 out; + tbl.
// K2 wd_mix: [0,9600) swizzled UNIFORM scale blocks (w=(bx&7)*1200+(bx>>3),
//    unit=(g,bh) gets 5 same-XCD consecutive blocks; preds loaded after
//    pooling, low VGPR). [9600,11520) dot0+18-wsum streaming blocks.
//    [11520,12160) mono blocks. Streaming tail fills the scale-block drain.
// K3 fin_pre + K4 finalize.
// Slots: [0..35] inter (pair*6+s), [36..71] sum_p, [72..89] sum_t, [90] mono.

#define DIMB 4
#define DIMD 28
#define DIMH 160
#define DIMW 160
#define HW   (DIMH * DIMW)
#define DHW  (DIMD * HW)
#define VOL_N (DIMB * DHW)      // 2,867,200
#define PGRID 640
#define NSLOTS 91
#define DICE_EPS 1e-7
#define TBL_OFF (480 * 1024)

__device__ __forceinline__ float u2f(int pos, int k, int L) {
    if (k == 1) return 1.f;
    int r = k >> 1;
    float s = 0.f;
    for (int j = max(pos - r, 0); j <= min(pos + r, L - 1); ++j)
        s += (float)(min(j + r, L - 1) - max(j - r, 0) + 1);
    return s / (float)(k * k);
}

__device__ __forceinline__ float wave_sum(float v) {
#pragma unroll
    for (int o = 1; o < 64; o <<= 1) v += __shfl_xor(v, o, 64);
    return v;
}

template<int K>
__device__ __forceinline__ void box4_col(float (&x)[28]) {
    constexpr int R = K / 2;
    constexpr float INVK = 1.f / (float)K;
#pragma unroll
    for (int p = 0; p < 4; ++p) {
        float y[28];
        float s = 0.f;
#pragma unroll
        for (int j = 0; j <= R; ++j) s += x[j];
        y[0] = s;
#pragma unroll
        for (int i = 1; i < 28; ++i) {
            if (i + R < 28) s += x[i + R];
            if (i - R - 1 >= 0) s -= x[i - R - 1];
            y[i] = s;
        }
#pragma unroll
        for (int i = 0; i < 28; ++i) x[i] = y[i] * INVK;
    }
}

// ---------------- K1: H-axis box^4 (all 5 scales from one raw load) --------
template<int K>
__device__ __forceinline__ void hstore(const float (&raw)[40],
                                       unsigned char* __restrict__ ob,
                                       int l, int c, int wl, int h0)
{
    constexpr int R = K / 2;
    constexpr float INVK = 1.f / (float)K;
    float ox[40];
#pragma unroll
    for (int i = 0; i < 40; ++i) ox[i] = raw[i];
#pragma unroll
    for (int pass = 0; pass < 4; ++pass) {
        float lo[R], hi[R];
#pragma unroll
        for (int i = 0; i < R; ++i) {
            float a = __shfl(ox[40 - R + i], l - 16, 64);
            lo[i] = (c == 0) ? 0.f : a;
            float b = __shfl(ox[i], l + 16, 64);
            hi[i] = (c == 3) ? 0.f : b;
        }
#define HWIN(j) ((j) < R ? lo[(j)] : ((j) < R + 40 ? ox[(j) - R] : hi[(j) - R - 40]))
        float out[40];
        float s = 0.f;
#pragma unroll
        for (int j = 0; j <= 2 * R; ++j) s += HWIN(j);
        out[0] = s * INVK;
#pragma unroll
        for (int i = 1; i < 40; ++i) {
            s += HWIN(i + 2 * R) - HWIN(i - 1);
            out[i] = s * INVK;
        }
#undef HWIN
#pragma unroll
        for (int i = 0; i < 40; ++i) ox[i] = out[i];
    }
#pragma unroll
    for (int i = 0; i < 40; ++i)
        ob[(h0 + i) * DIMW + wl] = (unsigned char)__float2uint_rn(ox[i] * 255.f);
}

__global__ __launch_bounds__(256) void hpool_tbl(const float* __restrict__ g0,
    const float* __restrict__ g1, const float* __restrict__ g2,
    unsigned char* __restrict__ bufs, float* __restrict__ tbl)
{
    int bx = blockIdx.x;
    if (bx < 840) {
        int u = bx * 2 + (threadIdx.x >> 7);   // 1680 units = 3g * 112bd * 5wt
        int tt = threadIdx.x & 127;
        int g = u / 560, r = u - g * 560;
        int bd = r / 5, wt = r - bd * 5;
        const float* in = (g == 0) ? g0 : (g == 1) ? g1 : g2;
        int l = tt & 63, v = tt >> 6;
        int c = l >> 4, wl = v * 16 + (l & 15), h0 = c * 40;
        const float* base = in + (size_t)bd * HW + wt * 32;
        float raw[40];
#pragma unroll
        for (int i = 0; i < 40; ++i) raw[i] = base[(h0 + i) * DIMW + wl];
        unsigned char* ob = bufs + (size_t)g * 5 * VOL_N + (size_t)bd * HW + wt * 32;
        hstore<5> (raw, ob + 0 * (size_t)VOL_N, l, c, wl, h0);
        hstore<13>(raw, ob + 1 * (size_t)VOL_N, l, c, wl, h0);
        hstore<23>(raw, ob + 2 * (size_t)VOL_N, l, c, wl, h0);
        hstore<31>(raw, ob + 3 * (size_t)VOL_N, l, c, wl, h0);
        hstore<41>(raw, ob + 4 * (size_t)VOL_N, l, c, wl, h0);
    } else {
        // u2f tables: tbl[0..959] = cW[6][160]; tbl[960..1127] = cD[6][28]
        const int KDa[6] = {1, 1, 3, 5, 7, 9};
        const int KHa[6] = {1, 5, 13, 23, 31, 41};
        for (int e = threadIdx.x; e < 1128; e += 256) {
            if (e < 960) tbl[e] = u2f(e % 160, KHa[e / 160], DIMH);
            else {
                int q = e - 960;
                tbl[e] = u2f(q % 28, KDa[q / 28], DIMD);
            }
        }
    }
}

// ---------------- K2: W-box^4 to S (shuffle halos, scale hoisted) ----------
template<int K>
__device__ __forceinline__ void wpool_to_S(const unsigned char* __restrict__ tb,
    float (*S)[164], int t, int l, int rr, int c, bool act)
{
    constexpr int R = K / 2;
    const float INV = 1.0f / (255.0f * (float)K * (float)K * (float)K * (float)K);
    float ox[20];
#pragma unroll
    for (int i = 0; i < 20; ++i) ox[i] = 0.f;
    if (act) {
        unsigned int u[5];
#pragma unroll
        for (int q = 0; q < 5; ++q) u[q] = *(const unsigned int*)(tb + 4 * q);
#pragma unroll
        for (int q = 0; q < 5; ++q) {
#pragma unroll
            for (int j = 0; j < 4; ++j)
                ox[4 * q + j] = (float)((u[q] >> (8 * j)) & 0xFFu);
        }
    }
#pragma unroll
    for (int pass = 0; pass < 4; ++pass) {
        float lo[R], hi[R];
#pragma unroll
        for (int i = 0; i < R; ++i) {
            float a = __shfl(ox[20 - R + i], l - 1, 64);
            lo[i] = (c == 0) ? 0.f : a;
            float b = __shfl(ox[i], l + 1, 64);
            hi[i] = (c == 7) ? 0.f : b;
        }
#define WWIN(j) ((j) < R ? lo[(j)] : ((j) < R + 20 ? ox[(j) - R] : hi[(j) - R - 20]))
        float out[20];
        float s = 0.f;
#pragma unroll
        for (int j = 0; j <= 2 * R; ++j) s += WWIN(j);
        out[0] = s;
#pragma unroll
        for (int i = 1; i < 20; ++i) {
            s += WWIN(i + 2 * R) - WWIN(i - 1);
            out[i] = s;
        }
#undef WWIN
#pragma unroll
        for (int i = 0; i < 20; ++i) ox[i] = out[i];
    }
    if (act) {
#pragma unroll
        for (int i = 0; i < 20; ++i) S[rr][c * 20 + i] = ox[i] * INV;
    }
    __syncthreads();
}

template<int K, int KD>
__device__ __forceinline__ void wd_scale(const unsigned char* __restrict__ tb,
    const float4* __restrict__ c4, const float4* __restrict__ p4, int base4,
    float (*S)[164], float* red2, int t, int l, int wid, int rr, int c, bool act,
    double* __restrict__ partials, int slot_c, int slot_p, int bh)
{
    wpool_to_S<K>(tb, S, t, l, rr, c, act);
    if constexpr (KD > 1) {
        if (t < DIMW) {
            float col[28];
#pragma unroll
            for (int j = 0; j < 28; ++j) col[j] = S[j][t];
            box4_col<KD>(col);
#pragma unroll
            for (int j = 0; j < 28; ++j) S[j][t] = col[j];
        }
        __syncthreads();
    }
    float aic = 0.f, aip = 0.f;
    for (int e4 = t; e4 < 1120; e4 += 256) {
        int dd = e4 / 40, w4 = e4 - dd * 40;
        int fi = base4 + dd * (HW / 4) + w4;
        float4 vc = c4[fi], vp = p4[fi];
        const float4 sv = *(const float4*)&S[dd][4 * w4];
        aic += vc.x * sv.x + vc.y * sv.y + vc.z * sv.z + vc.w * sv.w;
        aip += vp.x * sv.x + vp.y * sv.y + vp.z * sv.z + vp.w * sv.w;
    }
    float r1 = wave_sum(aic), r2 = wave_sum(aip);
    if (l == 0) { red2[wid * 2] = r1; red2[wid * 2 + 1] = r2; }
    __syncthreads();
    if (t < 2) {
        double rv = (double)red2[t] + red2[2 + t] + red2[4 + t] + red2[6 + t];
        partials[(size_t)(t == 0 ? slot_c : slot_p) * PGRID + bh] = rv;
    }
}

__global__ __launch_bounds__(256) void wd_mix(const unsigned char* __restrict__ bufs,
    const float* __restrict__ pc0, const float* __restrict__ pp0,
    const float* __restrict__ pc1, const float* __restrict__ pp1,
    const float* __restrict__ pc2, const float* __restrict__ pp2,
    const float* __restrict__ tr0, const float* __restrict__ tr1,
    const float* __restrict__ tr2, const float* __restrict__ o6,
    const float* __restrict__ tbl, double* __restrict__ partials)
{
    __shared__ __align__(16) float S[DIMD][164];
    __shared__ float redS[4][24];
    int bx0 = blockIdx.x;
    int t = threadIdx.x;

    if (bx0 < 9600) {
        // XCD-local swizzle: the 5 blocks of unit (g,bh) land on one XCD,
        // temporally adjacent (w consecutive -> bx stride 8).
        int w = (bx0 & 7) * 1200 + (bx0 >> 3);    // bijective (9600 = 8*1200)
        int u = w / 5, q = w - u * 5;             // q: 0=k41..4=k5
        int g = u / PGRID, bh = u - g * PGRID;
        int b = bh / DIMH, h = bh - b * DIMH;
        const float* pc = (g == 0) ? pc0 : (g == 1) ? pc1 : pc2;
        const float* pp = (g == 0) ? pp0 : (g == 1) ? pp1 : pp2;
        size_t base0 = (size_t)b * DHW + (size_t)h * DIMW;
        int base4 = b * (DHW / 4) + h * 40;
        const float4* c4 = (const float4*)pc;
        const float4* p4 = (const float4*)pp;
        int l = t & 63, wid = t >> 6;
        int rr = wid * 7 + (l >> 3), c = l & 7;
        bool act = (l < 56);
        int sbuf = 4 - q;                          // k41,k31,k23,k13,k5
        const unsigned char* tb = bufs + (size_t)(g * 5 + sbuf) * VOL_N
                                + base0 + (size_t)rr * HW + c * 20;
        int s = 5 - q;
        int slot_c = (2 * g) * 6 + s, slot_p = (2 * g + 1) * 6 + s;
        switch (q) {
            case 0: wd_scale<41, 9>(tb, c4, p4, base4, S, &redS[0][0], t, l, wid, rr, c, act, partials, slot_c, slot_p, bh); break;
            case 1: wd_scale<31, 7>(tb, c4, p4, base4, S, &redS[0][0], t, l, wid, rr, c, act, partials, slot_c, slot_p, bh); break;
            case 2: wd_scale<23, 5>(tb, c4, p4, base4, S, &redS[0][0], t, l, wid, rr, c, act, partials, slot_c, slot_p, bh); break;
            case 3: wd_scale<13, 3>(tb, c4, p4, base4, S, &redS[0][0], t, l, wid, rr, c, act, partials, slot_c, slot_p, bh); break;
            default: wd_scale<5, 1>(tb, c4, p4, base4, S, &redS[0][0], t, l, wid, rr, c, act, partials, slot_c, slot_p, bh); break;
        }
        return;
    }

    if (bx0 < 11520) {
        // dot0 + 18 weighted sums: pure streaming, fills the scale-drain tail
        int db = bx0 - 9600;                  // 1920 = 3g * 640
        int g = db / PGRID, blk = db - g * PGRID;
        const float* pc = (g == 0) ? pc0 : (g == 1) ? pc1 : pc2;
        const float* pp = (g == 0) ? pp0 : (g == 1) ? pp1 : pp2;
        const float* tr = (g == 0) ? tr0 : (g == 1) ? tr1 : tr2;
        const float4* c4p = (const float4*)pc;
        const float4* p4p = (const float4*)pp;
        const float4* t4p = (const float4*)tr;
        float vals[20];
#pragma unroll
        for (int i = 0; i < 20; ++i) vals[i] = 0.f;
        const int N4 = VOL_N / 4;
        for (int i4 = blk * 256 + t; i4 < N4; i4 += PGRID * 256) {
            int w4 = i4 % 40;
            int rest = i4 / 40;
            int h = rest % DIMH;
            int d = (rest / DIMH) % DIMD;
            float4 vc = c4p[i4], vp = p4p[i4], vt = t4p[i4];
            vals[0] += vc.x*vt.x + vc.y*vt.y + vc.z*vt.z + vc.w*vt.w;
            vals[1] += vp.x*vt.x + vp.y*vt.y + vp.z*vt.z + vp.w*vt.w;
#pragma unroll
            for (int s = 0; s < 6; ++s) {
                float cdh = tbl[960 + s * 28 + d] * tbl[s * 160 + h];
                const float4 cw = *(const float4*)(tbl + s * 160 + 4 * w4);
                vals[2 + s]  += cdh * (cw.x*vc.x + cw.y*vc.y + cw.z*vc.z + cw.w*vc.w);
                vals[8 + s]  += cdh * (cw.x*vp.x + cw.y*vp.y + cw.z*vp.z + cw.w*vp.w);
                vals[14 + s] += cdh * (cw.x*vt.x + cw.y*vt.y + cw.z*vt.z + cw.w*vt.w);
            }
        }
        int lane = t & 63, wid = t >> 6;
#pragma unroll
        for (int i = 0; i < 20; ++i) {
            float rv = wave_sum(vals[i]);
            if (lane == 0) redS[wid][i] = rv;
        }
        __syncthreads();
        if (t < 20) {
            double rv = (double)redS[0][t] + redS[1][t] + redS[2][t] + redS[3][t];
            int slot;
            if (t == 0) slot = (2 * g) * 6;
            else if (t == 1) slot = (2 * g + 1) * 6;
            else {
                int i = t - 2, vv = i / 6, s = i % 6;
                slot = (vv == 0) ? 36 + (2 * g) * 6 + s
                     : (vv == 1) ? 36 + (2 * g + 1) * 6 + s
                                 : 72 + g * 6 + s;
            }
            partials[(size_t)slot * PGRID + blk] = rv;
        }
        return;
    }

    // mono blocks
    int mb = bx0 - 11520;
    const int N4 = VOL_N / 4, PB = N4 / DIMB;
    float acc = 0.f;
    const float4* p = (const float4*)o6;
    for (int i = mb * 256 + t; i < N4; i += PGRID * 256) {
        int b = i / PB, r4 = i - b * PB;
        size_t a = (size_t)(b * 6) * PB + r4;
        float4 prev = p[a];
#pragma unroll
        for (int cc = 1; cc < 6; ++cc) {
            float4 cur = p[a + (size_t)cc * PB];
            acc += fmaxf(prev.x - cur.x, 0.f) + fmaxf(prev.y - cur.y, 0.f)
                 + fmaxf(prev.z - cur.z, 0.f) + fmaxf(prev.w - cur.w, 0.f);
            prev = cur;
        }
    }
    float rv = wave_sum(acc * 2.f);
    int lane = t & 63, wid = t >> 6;
    if (lane == 0) redS[wid][0] = rv;
    __syncthreads();
    if (t == 0)
        partials[(size_t)90 * PGRID + mb] =
            (double)redS[0][0] + redS[1][0] + redS[2][0] + redS[3][0];
}

// ---------------- K3/K4: reduction tail ----------------
__global__ __launch_bounds__(64) void fin_pre(const double* __restrict__ partials,
                                              double* __restrict__ ssum)
{
    int slot = blockIdx.x, t = threadIdx.x;
    double a = 0.0;
    for (int i = t; i < PGRID; i += 64) a += partials[(size_t)slot * PGRID + i];
#pragma unroll
    for (int o = 1; o < 64; o <<= 1) a += __shfl_xor(a, o, 64);
    if (t == 0) ssum[slot] = a;
}

__global__ void finalize(const double* __restrict__ ssum,
                         const float* __restrict__ off_a,
                         const float* __restrict__ off_b,
                         const float* __restrict__ off_ta,
                         const float* __restrict__ off_tb,
                         float* __restrict__ out)
{
    if (threadIdx.x == 0) {
        double loss = 0.0;
        for (int pair = 0; pair < 6; ++pair) {
            for (int s = 0; s < 6; ++s) {
                double inter = ssum[pair * 6 + s];
                double sp = ssum[36 + pair * 6 + s];
                double st = ssum[72 + (pair / 2) * 6 + s];
                loss += 0.2 * (1.0 - 2.0 * inter / (sp + st + DICE_EPS)) / 6.0;
            }
        }
        loss += 0.1 * (ssum[90] / (double)VOL_N);
        double oa = 0.0, ob = 0.0;
        for (int i = 0; i < 12; ++i) {
            oa += fabs((double)off_a[i] - (double)off_ta[i]);
            ob += fabs((double)off_b[i] - (double)off_tb[i]);
        }
        loss += 0.1 * (oa / 12.0) + 0.1 * (ob / 12.0);
        out[0] = (float)loss;
    }
}

extern "C" void kernel_launch(void* const* d_in, const int* in_sizes, int n_in,
                              void* d_out, int out_size, void* d_ws, size_t ws_size,
                              hipStream_t stream)
{
    double* partials = (double*)d_ws;                   // 91*640*8 = 465,920 B
    double* ssum = partials + (size_t)NSLOTS * PGRID;   // +91*8 < 480 KB
    float* tbl = (float*)((char*)d_ws + TBL_OFF);       // 1128 floats
    unsigned char* bufs = (unsigned char*)d_ws + 512 * 1024;  // 15*VOL_N u8 = 43 MB

    const float* pred[6] = {(const float*)d_in[0], (const float*)d_in[1],
                            (const float*)d_in[3], (const float*)d_in[4],
                            (const float*)d_in[6], (const float*)d_in[7]};
    const float* gt[3] = {(const float*)d_in[2], (const float*)d_in[5],
                          (const float*)d_in[8]};

    hpool_tbl<<<841, 256, 0, stream>>>(gt[0], gt[1], gt[2], bufs, tbl);
    wd_mix<<<12160, 256, 0, stream>>>(bufs, pred[0], pred[1], pred[2], pred[3],
                                      pred[4], pred[5], gt[0], gt[1], gt[2],
                                      (const float*)d_in[9], tbl, partials);
    fin_pre<<<NSLOTS, 64, 0, stream>>>(partials, ssum);
    finalize<<<1, 64, 0, stream>>>(ssum,
                                   (const float*)d_in[10], (const float*)d_in[11],
                                   (const float*)d_in[12], (const float*)d_in[13],
                                   (float*)d_out);
}

// Round 13
// 114.488 us; speedup vs baseline: 2.7113x; 1.1640x over previous
//
#include <hip/hip_runtime.h>
#include <hip/hip_fp16.h>

// Criterion_BiNet — adjoint multi-scale dice. R13 = R12 + packed-fp16
// dual-row scale blocks (each block pools TWO h-rows via __half2 SIMD).
// inter = p · (A^4 t); sum_p = p · (A^2 1); sum_t = t · (A^2 1).
// K1 hpool_tbl: H-axis box^4 for all 5 scales (shuffle halos), u8 out; + tbl.
// K2 wd_mix: [0,4800) swizzled dual-row scale blocks (w=(bx&7)*600+(bx>>3),
//    unit-pair (g,bhA=2j) gets 5 same-XCD consecutive blocks; rows h,h+1
//    packed in half2 lanes; per-pass 1/K rescale keeps fp16 in range).
//    [4800,6720) dot0+18-wsum streaming. [6720,7360) mono.
// K3 fin_pre + K4 finalize.
// Slots: [0..35] inter (pair*6+s), [36..71] sum_p, [72..89] sum_t, [90] mono.

#define DIMB 4
#define DIMD 28
#define DIMH 160
#define DIMW 160
#define HW   (DIMH * DIMW)
#define DHW  (DIMD * HW)
#define VOL_N (DIMB * DHW)      // 2,867,200
#define PGRID 640
#define NSLOTS 91
#define DICE_EPS 1e-7
#define TBL_OFF (480 * 1024)

__device__ __forceinline__ float u2f(int pos, int k, int L) {
    if (k == 1) return 1.f;
    int r = k >> 1;
    float s = 0.f;
    for (int j = max(pos - r, 0); j <= min(pos + r, L - 1); ++j)
        s += (float)(min(j + r, L - 1) - max(j - r, 0) + 1);
    return s / (float)(k * k);
}

__device__ __forceinline__ float wave_sum(float v) {
#pragma unroll
    for (int o = 1; o < 64; o <<= 1) v += __shfl_xor(v, o, 64);
    return v;
}

__device__ __forceinline__ __half2 shfl_h2(__half2 v, int src) {
    int x = __shfl(*reinterpret_cast<int*>(&v), src, 64);
    return *reinterpret_cast<__half2*>(&x);
}

// ---------------- K1: H-axis box^4 (all 5 scales from one raw load) --------
template<int K>
__device__ __forceinline__ void hstore(const float (&raw)[40],
                                       unsigned char* __restrict__ ob,
                                       int l, int c, int wl, int h0)
{
    constexpr int R = K / 2;
    constexpr float INVK = 1.f / (float)K;
    float ox[40];
#pragma unroll
    for (int i = 0; i < 40; ++i) ox[i] = raw[i];
#pragma unroll
    for (int pass = 0; pass < 4; ++pass) {
        float lo[R], hi[R];
#pragma unroll
        for (int i = 0; i < R; ++i) {
            float a = __shfl(ox[40 - R + i], l - 16, 64);
            lo[i] = (c == 0) ? 0.f : a;
            float b = __shfl(ox[i], l + 16, 64);
            hi[i] = (c == 3) ? 0.f : b;
        }
#define HWIN(j) ((j) < R ? lo[(j)] : ((j) < R + 40 ? ox[(j) - R] : hi[(j) - R - 40]))
        float out[40];
        float s = 0.f;
#pragma unroll
        for (int j = 0; j <= 2 * R; ++j) s += HWIN(j);
        out[0] = s * INVK;
#pragma unroll
        for (int i = 1; i < 40; ++i) {
            s += HWIN(i + 2 * R) - HWIN(i - 1);
            out[i] = s * INVK;
        }
#undef HWIN
#pragma unroll
        for (int i = 0; i < 40; ++i) ox[i] = out[i];
    }
#pragma unroll
    for (int i = 0; i < 40; ++i)
        ob[(h0 + i) * DIMW + wl] = (unsigned char)__float2uint_rn(ox[i] * 255.f);
}

__global__ __launch_bounds__(256) void hpool_tbl(const float* __restrict__ g0,
    const float* __restrict__ g1, const float* __restrict__ g2,
    unsigned char* __restrict__ bufs, float* __restrict__ tbl)
{
    int bx = blockIdx.x;
    if (bx < 840) {
        int u = bx * 2 + (threadIdx.x >> 7);   // 1680 units = 3g * 112bd * 5wt
        int tt = threadIdx.x & 127;
        int g = u / 560, r = u - g * 560;
        int bd = r / 5, wt = r - bd * 5;
        const float* in = (g == 0) ? g0 : (g == 1) ? g1 : g2;
        int l = tt & 63, v = tt >> 6;
        int c = l >> 4, wl = v * 16 + (l & 15), h0 = c * 40;
        const float* base = in + (size_t)bd * HW + wt * 32;
        float raw[40];
#pragma unroll
        for (int i = 0; i < 40; ++i) raw[i] = base[(h0 + i) * DIMW + wl];
        unsigned char* ob = bufs + (size_t)g * 5 * VOL_N + (size_t)bd * HW + wt * 32;
        hstore<5> (raw, ob + 0 * (size_t)VOL_N, l, c, wl, h0);
        hstore<13>(raw, ob + 1 * (size_t)VOL_N, l, c, wl, h0);
        hstore<23>(raw, ob + 2 * (size_t)VOL_N, l, c, wl, h0);
        hstore<31>(raw, ob + 3 * (size_t)VOL_N, l, c, wl, h0);
        hstore<41>(raw, ob + 4 * (size_t)VOL_N, l, c, wl, h0);
    } else {
        // u2f tables: tbl[0..959] = cW[6][160]; tbl[960..1127] = cD[6][28]
        const int KDa[6] = {1, 1, 3, 5, 7, 9};
        const int KHa[6] = {1, 5, 13, 23, 31, 41};
        for (int e = threadIdx.x; e < 1128; e += 256) {
            if (e < 960) tbl[e] = u2f(e % 160, KHa[e / 160], DIMH);
            else {
                int q = e - 960;
                tbl[e] = u2f(q % 28, KDa[q / 28], DIMD);
            }
        }
    }
}

// ---------------- K2: packed dual-row W-box^4 + D-box^4 + dots -------------
template<int K, int KD>
__device__ __forceinline__ void wd_scale_pk(const unsigned char* __restrict__ tbA,
    const float4* __restrict__ c4, const float4* __restrict__ p4, int base4,
    unsigned int (*S)[164], float (*redS)[4], int t, int l, int wid, int rr,
    int c, bool act, double* __restrict__ partials, int slot_c, int slot_p,
    int bhA)
{
    constexpr int R = K / 2;
    const __half2 INVK2 = __float2half2_rn(1.f / (float)K);
    const __half2 Z2 = __float2half2_rn(0.f);
    __half2 ox[20];
    if (act) {
        unsigned int uA[5], uB[5];
#pragma unroll
        for (int q = 0; q < 5; ++q) {
            uA[q] = *(const unsigned int*)(tbA + 4 * q);
            uB[q] = *(const unsigned int*)(tbA + DIMW + 4 * q);
        }
#pragma unroll
        for (int q = 0; q < 5; ++q) {
#pragma unroll
            for (int j = 0; j < 4; ++j) {
                float fA = (float)((uA[q] >> (8 * j)) & 0xFFu);
                float fB = (float)((uB[q] >> (8 * j)) & 0xFFu);
                ox[4 * q + j] = __floats2half2_rn(fA, fB);
            }
        }
    } else {
#pragma unroll
        for (int i = 0; i < 20; ++i) ox[i] = Z2;
    }
#pragma unroll
    for (int pass = 0; pass < 4; ++pass) {
        __half2 lo[R], hi[R];
#pragma unroll
        for (int i = 0; i < R; ++i) {
            __half2 a = shfl_h2(ox[20 - R + i], l - 1);
            lo[i] = (c == 0) ? Z2 : a;
            __half2 b = shfl_h2(ox[i], l + 1);
            hi[i] = (c == 7) ? Z2 : b;
        }
#define WWIN(j) ((j) < R ? lo[(j)] : ((j) < R + 20 ? ox[(j) - R] : hi[(j) - R - 20]))
        __half2 out[20];
        __half2 s = Z2;
#pragma unroll
        for (int j = 0; j <= 2 * R; ++j) s = __hadd2(s, WWIN(j));
        out[0] = __hmul2(s, INVK2);
#pragma unroll
        for (int i = 1; i < 20; ++i) {
            s = __hadd2(s, __hsub2(WWIN(i + 2 * R), WWIN(i - 1)));
            out[i] = __hmul2(s, INVK2);
        }
#undef WWIN
#pragma unroll
        for (int i = 0; i < 20; ++i) ox[i] = out[i];
    }
    if (act) {
#pragma unroll
        for (int i = 0; i < 20; ++i)
            S[rr][c * 20 + i] = *reinterpret_cast<unsigned int*>(&ox[i]);
    }
    __syncthreads();
    if constexpr (KD > 1) {
        constexpr int RD = KD / 2;
        const __half2 INVKD2 = __float2half2_rn(1.f / (float)KD);
        if (t < DIMW) {
            __half2 x[28];
#pragma unroll
            for (int j = 0; j < 28; ++j)
                x[j] = *reinterpret_cast<const __half2*>(&S[j][t]);
#pragma unroll
            for (int p = 0; p < 4; ++p) {
                __half2 y[28];
                __half2 s = Z2;
#pragma unroll
                for (int j = 0; j <= RD; ++j) s = __hadd2(s, x[j]);
                y[0] = s;
#pragma unroll
                for (int i = 1; i < 28; ++i) {
                    if (i + RD < 28) s = __hadd2(s, x[i + RD]);
                    if (i - RD - 1 >= 0) s = __hsub2(s, x[i - RD - 1]);
                    y[i] = s;
                }
#pragma unroll
                for (int i = 0; i < 28; ++i) x[i] = __hmul2(y[i], INVKD2);
            }
#pragma unroll
            for (int j = 0; j < 28; ++j)
                S[j][t] = *reinterpret_cast<unsigned int*>(&x[j]);
        }
        __syncthreads();
    }
    float aicA = 0.f, aipA = 0.f, aicB = 0.f, aipB = 0.f;
    for (int e4 = t; e4 < 1120; e4 += 256) {
        int dd = e4 / 40, w4 = e4 - dd * 40;
        int fi = base4 + dd * (HW / 4) + w4;
        float4 vcA = c4[fi],      vpA = p4[fi];
        float4 vcB = c4[fi + 40], vpB = p4[fi + 40];
        const uint4 sv = *(const uint4*)&S[dd][4 * w4];
        float2 s0 = __half22float2(*reinterpret_cast<const __half2*>(&sv.x));
        float2 s1 = __half22float2(*reinterpret_cast<const __half2*>(&sv.y));
        float2 s2 = __half22float2(*reinterpret_cast<const __half2*>(&sv.z));
        float2 s3 = __half22float2(*reinterpret_cast<const __half2*>(&sv.w));
        aicA += vcA.x*s0.x + vcA.y*s1.x + vcA.z*s2.x + vcA.w*s3.x;
        aipA += vpA.x*s0.x + vpA.y*s1.x + vpA.z*s2.x + vpA.w*s3.x;
        aicB += vcB.x*s0.y + vcB.y*s1.y + vcB.z*s2.y + vcB.w*s3.y;
        aipB += vpB.x*s0.y + vpB.y*s1.y + vpB.z*s2.y + vpB.w*s3.y;
    }
    const float SC = 1.f / 255.f;       // u8 decode factor
    float v0 = wave_sum(aicA) * SC, v1 = wave_sum(aipA) * SC;
    float v2 = wave_sum(aicB) * SC, v3 = wave_sum(aipB) * SC;
    if (l == 0) {
        redS[wid][0] = v0; redS[wid][1] = v1;
        redS[wid][2] = v2; redS[wid][3] = v3;
    }
    __syncthreads();
    if (t < 4) {
        double rv = (double)redS[0][t] + redS[1][t] + redS[2][t] + redS[3][t];
        int slot = (t & 1) ? slot_p : slot_c;
        int bh = bhA + (t >> 1);
        partials[(size_t)slot * PGRID + bh] = rv;
    }
}

__global__ __launch_bounds__(256) void wd_mix(const unsigned char* __restrict__ bufs,
    const float* __restrict__ pc0, const float* __restrict__ pp0,
    const float* __restrict__ pc1, const float* __restrict__ pp1,
    const float* __restrict__ pc2, const float* __restrict__ pp2,
    const float* __restrict__ tr0, const float* __restrict__ tr1,
    const float* __restrict__ tr2, const float* __restrict__ o6,
    const float* __restrict__ tbl, double* __restrict__ partials)
{
    __shared__ __align__(16) unsigned int S[DIMD][164];
    __shared__ float redS[4][24];
    int bx0 = blockIdx.x;
    int t = threadIdx.x;

    if (bx0 < 4800) {
        // XCD-local swizzle: 5 blocks of a unit-pair land on one XCD,
        // temporally adjacent (4800 = 8 * 600).
        int w = (bx0 & 7) * 600 + (bx0 >> 3);
        int u = w / 5, q = w - u * 5;         // q: 0=k41..4=k5
        int g = u / 320, pj = u - g * 320;
        int bhA = 2 * pj;
        int b = bhA / DIMH, h = bhA - b * DIMH;
        const float* pc = (g == 0) ? pc0 : (g == 1) ? pc1 : pc2;
        const float* pp = (g == 0) ? pp0 : (g == 1) ? pp1 : pp2;
        size_t base0 = (size_t)b * DHW + (size_t)h * DIMW;
        int base4 = b * (DHW / 4) + h * 40;
        const float4* c4 = (const float4*)pc;
        const float4* p4 = (const float4*)pp;
        int l = t & 63, wid = t >> 6;
        int rr = wid * 7 + (l >> 3), c = l & 7;
        bool act = (l < 56);
        int sbuf = 4 - q;                      // k41,k31,k23,k13,k5
        const unsigned char* tbA = bufs + (size_t)(g * 5 + sbuf) * VOL_N
                                 + base0 + (size_t)rr * HW + c * 20;
        int s = 5 - q;
        int slot_c = (2 * g) * 6 + s, slot_p = (2 * g + 1) * 6 + s;
        switch (q) {
            case 0: wd_scale_pk<41, 9>(tbA, c4, p4, base4, S, (float(*)[4])&redS[0][0], t, l, wid, rr, c, act, partials, slot_c, slot_p, bhA); break;
            case 1: wd_scale_pk<31, 7>(tbA, c4, p4, base4, S, (float(*)[4])&redS[0][0], t, l, wid, rr, c, act, partials, slot_c, slot_p, bhA); break;
            case 2: wd_scale_pk<23, 5>(tbA, c4, p4, base4, S, (float(*)[4])&redS[0][0], t, l, wid, rr, c, act, partials, slot_c, slot_p, bhA); break;
            case 3: wd_scale_pk<13, 3>(tbA, c4, p4, base4, S, (float(*)[4])&redS[0][0], t, l, wid, rr, c, act, partials, slot_c, slot_p, bhA); break;
            default: wd_scale_pk<5, 1>(tbA, c4, p4, base4, S, (float(*)[4])&redS[0][0], t, l, wid, rr, c, act, partials, slot_c, slot_p, bhA); break;
        }
        return;
    }

    if (bx0 < 6720) {
        // dot0 + 18 weighted sums: pure streaming, fills the scale-drain tail
        int db = bx0 - 4800;                  // 1920 = 3g * 640
        int g = db / PGRID, blk = db - g * PGRID;
        const float* pc = (g == 0) ? pc0 : (g == 1) ? pc1 : pc2;
        const float* pp = (g == 0) ? pp0 : (g == 1) ? pp1 : pp2;
        const float* tr = (g == 0) ? tr0 : (g == 1) ? tr1 : tr2;
        const float4* c4p = (const float4*)pc;
        const float4* p4p = (const float4*)pp;
        const float4* t4p = (const float4*)tr;
        float vals[20];
#pragma unroll
        for (int i = 0; i < 20; ++i) vals[i] = 0.f;
        const int N4 = VOL_N / 4;
        for (int i4 = blk * 256 + t; i4 < N4; i4 += PGRID * 256) {
            int w4 = i4 % 40;
            int rest = i4 / 40;
            int h = rest % DIMH;
            int d = (rest / DIMH) % DIMD;
            float4 vc = c4p[i4], vp = p4p[i4], vt = t4p[i4];
            vals[0] += vc.x*vt.x + vc.y*vt.y + vc.z*vt.z + vc.w*vt.w;
            vals[1] += vp.x*vt.x + vp.y*vt.y + vp.z*vt.z + vp.w*vt.w;
#pragma unroll
            for (int s = 0; s < 6; ++s) {
                float cdh = tbl[960 + s * 28 + d] * tbl[s * 160 + h];
                const float4 cw = *(const float4*)(tbl + s * 160 + 4 * w4);
                vals[2 + s]  += cdh * (cw.x*vc.x + cw.y*vc.y + cw.z*vc.z + cw.w*vc.w);
                vals[8 + s]  += cdh * (cw.x*vp.x + cw.y*vp.y + cw.z*vp.z + cw.w*vp.w);
                vals[14 + s] += cdh * (cw.x*vt.x + cw.y*vt.y + cw.z*vt.z + cw.w*vt.w);
            }
        }
        int lane = t & 63, wid = t >> 6;
#pragma unroll
        for (int i = 0; i < 20; ++i) {
            float rv = wave_sum(vals[i]);
            if (lane == 0) redS[wid][i] = rv;
        }
        __syncthreads();
        if (t < 20) {
            double rv = (double)redS[0][t] + redS[1][t] + redS[2][t] + redS[3][t];
            int slot;
            if (t == 0) slot = (2 * g) * 6;
            else if (t == 1) slot = (2 * g + 1) * 6;
            else {
                int i = t - 2, vv = i / 6, s = i % 6;
                slot = (vv == 0) ? 36 + (2 * g) * 6 + s
                     : (vv == 1) ? 36 + (2 * g + 1) * 6 + s
                                 : 72 + g * 6 + s;
            }
            partials[(size_t)slot * PGRID + blk] = rv;
        }
        return;
    }

    // mono blocks
    int mb = bx0 - 6720;
    const int N4 = VOL_N / 4, PB = N4 / DIMB;
    float acc = 0.f;
    const float4* p = (const float4*)o6;
    for (int i = mb * 256 + t; i < N4; i += PGRID * 256) {
        int b = i / PB, r4 = i - b * PB;
        size_t a = (size_t)(b * 6) * PB + r4;
        float4 prev = p[a];
#pragma unroll
        for (int cc = 1; cc < 6; ++cc) {
            float4 cur = p[a + (size_t)cc * PB];
            acc += fmaxf(prev.x - cur.x, 0.f) + fmaxf(prev.y - cur.y, 0.f)
                 + fmaxf(prev.z - cur.z, 0.f) + fmaxf(prev.w - cur.w, 0.f);
            prev = cur;
        }
    }
    float rv = wave_sum(acc * 2.f);
    int lane = t & 63, wid = t >> 6;
    if (lane == 0) redS[wid][0] = rv;
    __syncthreads();
    if (t == 0)
        partials[(size_t)90 * PGRID + mb] =
            (double)redS[0][0] + redS[1][0] + redS[2][0] + redS[3][0];
}

// ---------------- K3/K4: reduction tail ----------------
__global__ __launch_bounds__(64) void fin_pre(const double* __restrict__ partials,
                                              double* __restrict__ ssum)
{
    int slot = blockIdx.x, t = threadIdx.x;
    double a = 0.0;
    for (int i = t; i < PGRID; i += 64) a += partials[(size_t)slot * PGRID + i];
#pragma unroll
    for (int o = 1; o < 64; o <<= 1) a += __shfl_xor(a, o, 64);
    if (t == 0) ssum[slot] = a;
}

__global__ void finalize(const double* __restrict__ ssum,
                         const float* __restrict__ off_a,
                         const float* __restrict__ off_b,
                         const float* __restrict__ off_ta,
                         const float* __restrict__ off_tb,
                         float* __restrict__ out)
{
    if (threadIdx.x == 0) {
        double loss = 0.0;
        for (int pair = 0; pair < 6; ++pair) {
            for (int s = 0; s < 6; ++s) {
                double inter = ssum[pair * 6 + s];
                double sp = ssum[36 + pair * 6 + s];
                double st = ssum[72 + (pair / 2) * 6 + s];
                loss += 0.2 * (1.0 - 2.0 * inter / (sp + st + DICE_EPS)) / 6.0;
            }
        }
        loss += 0.1 * (ssum[90] / (double)VOL_N);
        double oa = 0.0, ob = 0.0;
        for (int i = 0; i < 12; ++i) {
            oa += fabs((double)off_a[i] - (double)off_ta[i]);
            ob += fabs((double)off_b[i] - (double)off_tb[i]);
        }
        loss += 0.1 * (oa / 12.0) + 0.1 * (ob / 12.0);
        out[0] = (float)loss;
    }
}

extern "C" void kernel_launch(void* const* d_in, const int* in_sizes, int n_in,
                              void* d_out, int out_size, void* d_ws, size_t ws_size,
                              hipStream_t stream)
{
    double* partials = (double*)d_ws;                   // 91*640*8 = 465,920 B
    double* ssum = partials + (size_t)NSLOTS * PGRID;   // +91*8 < 480 KB
    float* tbl = (float*)((char*)d_ws + TBL_OFF);       // 1128 floats
    unsigned char* bufs = (unsigned char*)d_ws + 512 * 1024;  // 15*VOL_N u8 = 43 MB

    const float* pred[6] = {(const float*)d_in[0], (const float*)d_in[1],
                            (const float*)d_in[3], (const float*)d_in[4],
                            (const float*)d_in[6], (const float*)d_in[7]};
    const float* gt[3] = {(const float*)d_in[2], (const float*)d_in[5],
                          (const float*)d_in[8]};

    hpool_tbl<<<841, 256, 0, stream>>>(gt[0], gt[1], gt[2], bufs, tbl);
    wd_mix<<<7360, 256, 0, stream>>>(bufs, pred[0], pred[1], pred[2], pred[3],
                                     pred[4], pred[5], gt[0], gt[1], gt[2],
                                     (const float*)d_in[9], tbl, partials);
    fin_pre<<<NSLOTS, 64, 0, stream>>>(partials, ssum);
    finalize<<<1, 64, 0, stream>>>(ssum,
                                   (const float*)d_in[10], (const float*)d_in[11],
                                   (const float*)d_in[12], (const float*)d_in[13],
                                   (float*)d_out);
}